// Round 10
// baseline (603.413 us; speedup 1.0000x reference)
//
#include <hip/hip_runtime.h>

// IJGNN attention-MPNN, 3 iterations. fp32 in/out, bf16 internal.
// Edges processed in dst-sorted (CSR) order; edge head scatters back via eid.
// This rev: round-7 configuration (best measured, 593.5us) with two kept
// deltas: (a) LAST out_ef scatter vectorized (f32 restage through Mt -> 32B
// stores), (b) prep_weights nf-fold. XCD swizzle REMOVED (round-9 A/B: -10us
// regression -- Xs/Xd reuse is already L3-resident; remap only disrupted the
// sequential HEF stream).

#define GN 25000
#define GE 400000
#define NODE_BLKS 196    // ceil(GN/128)
#define EDGE_BLKS 6250   // GE/64 exact (edge_fused tiles)

typedef unsigned short u16;
typedef __attribute__((ext_vector_type(8))) short bf16x8;
typedef __attribute__((ext_vector_type(4))) float f32x4;

__device__ inline float b2f(u16 v) {
  union { unsigned int u; float f; } x; x.u = ((unsigned int)v) << 16; return x.f;
}
__device__ inline u16 f2b(float f) {
  union { float f; unsigned int u; } x; x.f = f;
  unsigned int u = x.u;
  u += 0x7fffu + ((u >> 16) & 1u);
  return (u16)(u >> 16);
}

// ---------------- dtype probe ----------------
__global__ void detect_dtype(const void* nf, int* flag) {
  if (blockIdx.x == 0 && threadIdx.x == 0) {
    const u16* p = (const u16*)nf;
    int cnt = 0;
    for (int i = 0; i < 512; i += 2) {
      int e = (p[i] >> 7) & 0xFF;
      if (e >= 0x70 && e <= 0x85) cnt++;
    }
    *flag = (cnt < 128) ? 1 : 0;
  }
}

// gather ef rows into dst-sorted order (+convert), 16B per thread
__global__ void gather_ef(const void* ef, const int* eid, u16* efc, const int* flag) {
  int f32 = *flag;
  long idx = (long)blockIdx.x * blockDim.x + threadIdx.x;
  long ntot = (long)GE * 4;  // 8-col groups
  if (idx >= ntot) return;
  long j = idx >> 2;
  int g = (int)(idx & 3) * 8;
  long e = eid[j];
  uint4 out;
  if (f32) {
    const float* pf = (const float*)ef + e * 32 + g;
    float4 a = ((const float4*)pf)[0];
    float4 b = ((const float4*)pf)[1];
    unsigned int* ov = (unsigned int*)&out;
    ov[0] = (unsigned int)f2b(a.x) | ((unsigned int)f2b(a.y) << 16);
    ov[1] = (unsigned int)f2b(a.z) | ((unsigned int)f2b(a.w) << 16);
    ov[2] = (unsigned int)f2b(b.x) | ((unsigned int)f2b(b.y) << 16);
    ov[3] = (unsigned int)f2b(b.z) | ((unsigned int)f2b(b.w) << 16);
  } else {
    out = *(const uint4*)((const u16*)ef + e * 32 + g);
  }
  *(uint4*)(efc + j * 32 + g) = out;
}

// ---------------- weight prep + nf convert, one launch ----------------
__global__ void prep_weights(const void* We, const void* Wn, const void* Wa,
                             const void* Won, const void* Woe,
                             const void* be, const void* ba, const void* bn,
                             const void* bno, const void* beo, const void* nf,
                             u16* WeT, u16* WnpT, u16* WnuT, u16* WoN, u16* WoE,
                             u16* Wac, u16* bec, u16* bac, u16* bnc, u16* bnoc, u16* beoc,
                             u16* nfc, const int* flag) {
  int f32 = *flag;
  auto ld = [&](const void* p, long i) -> u16 {
    return f32 ? f2b(((const float*)p)[i]) : ((const u16*)p)[i];
  };
  int tid = blockIdx.x * blockDim.x + threadIdx.x;
  int nt = gridDim.x * blockDim.x;
  for (long i = tid; i < (long)GN * 32; i += nt) nfc[i] = ld(nf, i);
  for (int i = tid; i < 128 * 160; i += nt) { int n = i / 160, k = i % 160; WeT[i] = ld(We, (long)(320 + k) * 128 + n); }
  for (int i = tid; i < 256 * 160; i += nt) {
    int c = i / 160, k = i % 160;
    WnpT[i] = (c < 128) ? ld(We, (long)k * 128 + c) : ld(We, (long)(160 + k) * 128 + (c - 128));
  }
  for (int i = tid; i < 128 * 288; i += nt) { int c = i / 288, k = i % 288; WnuT[i] = ld(Wn, (long)k * 128 + c); }
  for (int i = tid; i < 32 * 128; i += nt) {
    int c = i / 128, k = i % 128;
    WoN[i] = ld(Won, (long)k * 32 + c);
    WoE[i] = ld(Woe, (long)k * 32 + c);
  }
  for (int i = tid; i < 480; i += nt) Wac[i] = ld(Wa, i);
  for (int i = tid; i < 128; i += nt) { bec[i] = ld(be, i); bnc[i] = ld(bn, i); }
  for (int i = tid; i < 32; i += nt) { bnoc[i] = ld(bno, i); beoc[i] = ld(beo, i); }
  if (tid == 0) bac[0] = ld(ba, 0);
}

// ---------------- CSR build ----------------
__global__ void hist_kernel(const int* dst, int* counts, int n) {
  for (int e = blockIdx.x * blockDim.x + threadIdx.x; e < n; e += gridDim.x * blockDim.x)
    atomicAdd(&counts[dst[e]], 1);
}

__global__ __launch_bounds__(1024) void scan_kernel(int* cursor, int* rowptr, int n) {
  __shared__ int part[1024];
  int t = threadIdx.x;
  int per = (n + 1023) / 1024;
  int lo = t * per;
  int hi = lo + per; if (hi > n) hi = n;
  if (lo > n) lo = n;
  int s = 0;
  for (int i = lo; i < hi; ++i) s += cursor[i];
  part[t] = s;
  __syncthreads();
  for (int off = 1; off < 1024; off <<= 1) {
    int v = (t >= off) ? part[t - off] : 0;
    __syncthreads();
    part[t] += v;
    __syncthreads();
  }
  int run = (t > 0) ? part[t - 1] : 0;
  for (int i = lo; i < hi; ++i) {
    int c = cursor[i];
    cursor[i] = run;
    rowptr[i + 1] = run + c;
    run += c;
  }
  if (t == 0) rowptr[0] = 0;
}

// fill CSR order + gather src/dst meta in the same pass
__global__ void fill_kernel(const int* src, const int* dst, int* cursor, int* eid,
                            int* srcs, int* dsts, int n) {
  for (int e = blockIdx.x * blockDim.x + threadIdx.x; e < n; e += gridDim.x * blockDim.x) {
    int d = dst[e];
    int p = atomicAdd(&cursor[d], 1);
    eid[p] = e;
    srcs[p] = src[e];
    dsts[p] = d;
  }
}

// ---------------- node projections (MFMA): Xs/Xd [N,128] bf16, as/ad [N] fp32 ----------------
__global__ __launch_bounds__(256)
void node_proj(const u16* HNF, const u16* nf, const u16* WnpT, const u16* W_attn,
               u16* Xs, u16* Xd, float* as_, float* ad_, int kc0, int nrows) {
  __shared__ union {
    struct { __align__(16) u16 A[128][40]; __align__(16) u16 B[128][40]; } st;
    u16 C[128][130];  // bf16 transpose buffer (final values; no extra rounding)
  } sm;
  __shared__ float dotbuf[128][2];
  int sel = blockIdx.y, blk = blockIdx.x, tid = threadIdx.x;
  int lane = tid & 63, wv = tid >> 6, wr = wv & 1, wc = wv >> 1;
  const u16* BT = WnpT + sel * 128 * 160;
  u16* OUT = sel ? Xd : Xs;
  float* AOUT = sel ? ad_ : as_;
  const u16* wa = W_attn + sel * 160;
  f32x4 acc[4][4];
  f32x4 zf = {0.f, 0.f, 0.f, 0.f};
  for (int i = 0; i < 4; ++i) for (int j = 0; j < 4; ++j) acc[i][j] = zf;
  float dp = 0.f;
  int arow = tid >> 1, ahalf = (tid & 1) * 16;
  int r0 = blk * 128;
  int ra = r0 + arow;
  uint4 va0 = make_uint4(0, 0, 0, 0), va1 = make_uint4(0, 0, 0, 0), vb0, vb1;
  {
    if (ra < nrows) {
      const uint4* p = (kc0 < 4) ? (const uint4*)(HNF + (size_t)ra * 128 + kc0 * 32 + ahalf)
                                 : (const uint4*)(nf + (size_t)ra * 32 + ahalf);
      va0 = p[0]; va1 = p[1];
    }
    const uint4* pb = (const uint4*)(BT + arow * 160 + kc0 * 32 + ahalf);
    vb0 = pb[0]; vb1 = pb[1];
  }
  for (int kc = kc0; kc < 5; ++kc) {
    *(uint4*)&sm.st.A[arow][ahalf] = va0;
    *(uint4*)&sm.st.A[arow][ahalf + 8] = va1;
    *(uint4*)&sm.st.B[arow][ahalf] = vb0;
    *(uint4*)&sm.st.B[arow][ahalf + 8] = vb1;
    if (kc < 4) {  // prefetch next chunk
      int kn = kc + 1;
      va0 = make_uint4(0, 0, 0, 0); va1 = make_uint4(0, 0, 0, 0);
      if (ra < nrows) {
        const uint4* p = (kn < 4) ? (const uint4*)(HNF + (size_t)ra * 128 + kn * 32 + ahalf)
                                  : (const uint4*)(nf + (size_t)ra * 32 + ahalf);
        va0 = p[0]; va1 = p[1];
      }
      const uint4* pb = (const uint4*)(BT + arow * 160 + kn * 32 + ahalf);
      vb0 = pb[0]; vb1 = pb[1];
    }
    __syncthreads();
    {
      float s = 0.f;
      for (int j = 0; j < 16; ++j) s += b2f(sm.st.A[arow][ahalf + j]) * b2f(wa[kc * 32 + ahalf + j]);
      dp += s;
    }
    int q = lane >> 4, l16 = lane & 15;
    bf16x8 af[4], bfr[4];
    for (int i = 0; i < 4; ++i) af[i] = *(const bf16x8*)&sm.st.A[wr * 64 + i * 16 + l16][q * 8];
    for (int j = 0; j < 4; ++j) bfr[j] = *(const bf16x8*)&sm.st.B[wc * 64 + j * 16 + l16][q * 8];
    for (int i = 0; i < 4; ++i)
      for (int j = 0; j < 4; ++j)
        acc[i][j] = __builtin_amdgcn_mfma_f32_16x16x32_bf16(af[i], bfr[j], acc[i][j], 0, 0, 0);
    __syncthreads();
  }
  dotbuf[arow][tid & 1] = dp;
  // scatter acc -> LDS transpose buffer (overlays staging; K-loop is done)
  {
    int q = lane >> 4, l16 = lane & 15;
    for (int i = 0; i < 4; ++i)
      for (int j = 0; j < 4; ++j) {
        int col = wc * 64 + j * 16 + l16;
        for (int rr = 0; rr < 4; ++rr) {
          int row = wr * 64 + i * 16 + q * 4 + rr;
          sm.C[row][col] = f2b(acc[i][j][rr]);
        }
      }
  }
  __syncthreads();
  if (tid < 128) {
    int r = r0 + tid;
    if (r < nrows) AOUT[r] = dotbuf[tid][0] + dotbuf[tid][1];
  }
  // vectorized store: each thread owns one row-half (64 cols = 8x dwordx4)
  {
    int r = tid >> 1, h = (tid & 1) * 64;
    int rg = r0 + r;
    if (rg < nrows) {
      uint4* po = (uint4*)(OUT + (size_t)rg * 128 + h);
      for (int k = 0; k < 8; ++k) {
        unsigned int a0 = *(const unsigned int*)&sm.C[r][h + k * 8];
        unsigned int a1 = *(const unsigned int*)&sm.C[r][h + k * 8 + 2];
        unsigned int a2 = *(const unsigned int*)&sm.C[r][h + k * 8 + 4];
        unsigned int a3 = *(const unsigned int*)&sm.C[r][h + k * 8 + 6];
        po[k] = make_uint4(a0, a1, a2, a3);
      }
    }
  }
}

// ---------------- edge stage: 64-edge tiles, A dbuf LDS, B frags from L2 (ping-pong) ----------------
// Round-7 body (best measured; natural block order). LAST=1: fused edge head;
// out_ef staged through Mt as f32, written as 32B vectors at eid rows.
template <int KC0, int LAST>
__global__ __launch_bounds__(256, 4)
void edge_fused(u16* HEF, const u16* ef, const u16* WeT, const u16* W_attn,
                const u16* b_edge, const u16* b_attn, const int* srcs, const int* dsts,
                const u16* Xs, const u16* Xd, const float* as_, const float* ad_,
                float* logit, const u16* WoE, const u16* b_eout, const int* eid,
                float* out_ef) {
  __shared__ union {
    __align__(16) u16 A[2][64][40];  // double-buffered A chunk (10.2KB)
    float C[64][65];                 // epilogue transpose (16.6KB); bank spread
  } sm;
  __shared__ float dotbuf[64];
  __shared__ __align__(16) u16 Mt[LAST ? 64 : 1][136];  // bf16 M tile / f32 head stage
  int blk = blockIdx.x, tid = threadIdx.x;
  int lane = tid & 63, wv = tid >> 6, wr = wv & 1, wc = wv >> 1;
  int q = lane >> 4, l16 = lane & 15;
  f32x4 acc[2][4];
  f32x4 zf = {0.f, 0.f, 0.f, 0.f};
  for (int i = 0; i < 2; ++i) for (int j = 0; j < 4; ++j) acc[i][j] = zf;
  float dp[2] = {0.f, 0.f};
  long e0 = (long)blk * 64;
  long ea = e0 + (tid >> 2);
  int qp = (tid & 3) * 8;  // A col offset (u16 units), 16B per thread
  const u16* wa = W_attn + 320;

  uint4 va = (KC0 < 4) ? *(const uint4*)(HEF + ea * 128 + KC0 * 32 + qp)
                       : *(const uint4*)(ef + ea * 32 + qp);
  bf16x8 bfp[2][4];
#pragma unroll
  for (int j = 0; j < 4; ++j)
    bfp[KC0 & 1][j] = *(const bf16x8*)(WeT + (size_t)(wc * 64 + j * 16 + l16) * 160 + KC0 * 32 + q * 8);

#pragma unroll
  for (int kc = KC0; kc < 5; ++kc) {
    int buf = kc & 1;
    *(uint4*)&sm.A[buf][tid >> 2][qp] = va;
    if (kc < 4) {  // issue next-chunk loads; latency hides under barrier+MFMA
      va = (kc + 1 < 4) ? *(const uint4*)(HEF + ea * 128 + (kc + 1) * 32 + qp)
                        : *(const uint4*)(ef + ea * 32 + qp);
#pragma unroll
      for (int j = 0; j < 4; ++j)
        bfp[(kc + 1) & 1][j] = *(const bf16x8*)(WeT + (size_t)(wc * 64 + j * 16 + l16) * 160 + (kc + 1) * 32 + q * 8);
    }
    __syncthreads();
    bf16x8 af[2];
    for (int i = 0; i < 2; ++i) af[i] = *(const bf16x8*)&sm.A[buf][wr * 32 + i * 16 + l16][q * 8];
    if (wc == 0) {
      bf16x8 wv8 = *(const bf16x8*)&wa[kc * 32 + q * 8];
      float wf[8];
      for (int j = 0; j < 8; ++j) wf[j] = b2f((u16)wv8[j]);
      for (int i = 0; i < 2; ++i)
        for (int j = 0; j < 8; ++j) dp[i] += b2f((u16)af[i][j]) * wf[j];
    }
    for (int i = 0; i < 2; ++i)
      for (int j = 0; j < 4; ++j)
        acc[i][j] = __builtin_amdgcn_mfma_f32_16x16x32_bf16(af[i], bfp[buf][j], acc[i][j], 0, 0, 0);
  }
  if (wc == 0) {
    for (int i = 0; i < 2; ++i) {
      dp[i] += __shfl_xor(dp[i], 16);
      dp[i] += __shfl_xor(dp[i], 32);
    }
    if (q == 0)
      for (int i = 0; i < 2; ++i) dotbuf[wr * 32 + i * 16 + l16] = dp[i];
  }
  int r = tid >> 2, qh = tid & 3;  // each thread: one edge row, 16 cols/pass
  long e = e0 + r;
  int s = srcs[e], d = dsts[e];
#pragma unroll
  for (int p = 0; p < 2; ++p) {
    int cb = p * 64 + qh * 16;
    // issue vector gathers early: latency hides under barrier + LDS scatter
    const uint4* ps = (const uint4*)(Xs + (size_t)s * 128 + cb);
    const uint4* pd = (const uint4*)(Xd + (size_t)d * 128 + cb);
    uint4 gs0 = ps[0], gs1 = ps[1], gd0 = pd[0], gd1 = pd[1];
    // p=0: wait for all waves' last A-reads + dotbuf writes before overlaying C
    // p=1: wait for pass-0 C reads before rewriting C
    __syncthreads();
    if (wc == p) {  // this wave pair's acc covers cols [p*64, p*64+64)
      for (int i = 0; i < 2; ++i)
        for (int j = 0; j < 4; ++j) {
          int col = j * 16 + l16;
          float bb = b2f(b_edge[p * 64 + col]);
          for (int rr = 0; rr < 4; ++rr)
            sm.C[wr * 32 + i * 16 + q * 4 + rr][col] = acc[i][j][rr] + bb;
        }
    }
    __syncthreads();
    if (p == 0 && tid < 64) {
      long ee = e0 + tid;
      logit[ee] = dotbuf[tid] + as_[srcs[ee]] + ad_[dsts[ee]] + b2f(b_attn[0]);
    }
    unsigned int us[8], ud[8];
    *(uint4*)&us[0] = gs0; *(uint4*)&us[4] = gs1;
    *(uint4*)&ud[0] = gd0; *(uint4*)&ud[4] = gd1;
    unsigned int ov[8];
    for (int w = 0; w < 8; ++w) {
      float c0 = sm.C[r][qh * 16 + 2 * w];
      float c1 = sm.C[r][qh * 16 + 2 * w + 1];
      float v0 = c0 + b2f((u16)(us[w] & 0xffffu)) + b2f((u16)(ud[w] & 0xffffu));
      float v1 = c1 + b2f((u16)(us[w] >> 16)) + b2f((u16)(ud[w] >> 16));
      ov[w] = (unsigned int)f2b(fmaxf(v0, 0.f)) | ((unsigned int)f2b(fmaxf(v1, 0.f)) << 16);
    }
    if constexpr (LAST) {  // stash M for the fused head GEMM (same bf16 bits)
      *(uint4*)&Mt[r][cb] = *(uint4*)&ov[0];
      *(uint4*)&Mt[r][cb + 8] = *(uint4*)&ov[4];
    }
    uint4* po = (uint4*)(HEF + e * 128 + cb);
    po[0] = *(uint4*)&ov[0];
    po[1] = *(uint4*)&ov[4];
  }
  if constexpr (LAST) {
    __syncthreads();  // all Mt writes visible
    f32x4 ha0 = zf, ha1 = zf;  // wave wv: out rows [wv*16, +16), 32 cols
#pragma unroll
    for (int kc2 = 0; kc2 < 4; ++kc2) {
      bf16x8 af2 = *(const bf16x8*)&Mt[wv * 16 + l16][kc2 * 32 + q * 8];
      bf16x8 b0 = *(const bf16x8*)(WoE + (size_t)l16 * 128 + kc2 * 32 + q * 8);
      bf16x8 b1 = *(const bf16x8*)(WoE + (size_t)(16 + l16) * 128 + kc2 * 32 + q * 8);
      ha0 = __builtin_amdgcn_mfma_f32_16x16x32_bf16(af2, b0, ha0, 0, 0, 0);
      ha1 = __builtin_amdgcn_mfma_f32_16x16x32_bf16(af2, b1, ha1, 0, 0, 0);
    }
    __syncthreads();  // all Mt GEMM reads done before f32 restage
    float* Mf = (float*)&Mt[0][0];  // [64][34] f32 head-output stage (8.7KB)
    float bb0 = b2f(b_eout[l16]), bb1 = b2f(b_eout[16 + l16]);
    for (int rr = 0; rr < 4; ++rr) {
      int row = wv * 16 + q * 4 + rr;
      Mf[row * 34 + l16] = ha0[rr] + bb0;
      Mf[row * 34 + 16 + l16] = ha1[rr] + bb1;
    }
    __syncthreads();
    {  // vectorized eid-scattered store: 4 threads x 32B cover one 128B row
      int rr2 = tid >> 2, c0 = (tid & 3) * 8;
      long ro = eid[e0 + rr2];
      uint4 w0 = *(const uint4*)&Mf[rr2 * 34 + c0];
      uint4 w1 = *(const uint4*)&Mf[rr2 * 34 + c0 + 4];
      uint4* po = (uint4*)(out_ef + ro * 32 + c0);
      po[0] = w0; po[1] = w1;
    }
  }
}

// ---------------- per-dst softmax + aggregation ----------------
__global__ __launch_bounds__(256)
void aggregate(const int* rowptr, const float* logit, const u16* M, u16* AGG, int nrows) {
  int gw = (blockIdx.x * blockDim.x + threadIdx.x) >> 6;
  int lane = threadIdx.x & 63;
  if (gw >= nrows) return;
  int beg = rowptr[gw], end = rowptr[gw + 1];
  int sub = lane >> 3, cl = lane & 7;
  float mx = -1e30f;
  for (int j = beg + lane; j < end; j += 64) mx = fmaxf(mx, logit[j]);
  for (int off = 32; off > 0; off >>= 1) mx = fmaxf(mx, __shfl_xor(mx, off));
  float acc[16];
  for (int t = 0; t < 16; ++t) acc[t] = 0.f;
  float denom = 0.f;
  float wc = 0.f;
  uint4 m0c = make_uint4(0, 0, 0, 0), m1c = make_uint4(0, 0, 0, 0);
  {
    int j = beg + sub;
    if (j < end) {
      wc = __expf(logit[j] - mx);
      const uint4* mp = (const uint4*)(M + (size_t)j * 128 + cl * 16);
      m0c = mp[0]; m1c = mp[1];
    }
  }
  for (int j0 = beg; j0 < end; j0 += 8) {
    float wn = 0.f;
    uint4 m0n = make_uint4(0, 0, 0, 0), m1n = make_uint4(0, 0, 0, 0);
    int jn = j0 + 8 + sub;
    if (jn < end) {
      wn = __expf(logit[jn] - mx);
      const uint4* mp = (const uint4*)(M + (size_t)jn * 128 + cl * 16);
      m0n = mp[0]; m1n = mp[1];
    }
    denom += wc;
    const unsigned int* mw0 = (const unsigned int*)&m0c;
    const unsigned int* mw1 = (const unsigned int*)&m1c;
    for (int t = 0; t < 4; ++t) {
      acc[2 * t]     += wc * b2f((u16)(mw0[t] & 0xffffu));
      acc[2 * t + 1] += wc * b2f((u16)(mw0[t] >> 16));
      acc[8 + 2 * t]     += wc * b2f((u16)(mw1[t] & 0xffffu));
      acc[8 + 2 * t + 1] += wc * b2f((u16)(mw1[t] >> 16));
    }
    wc = wn; m0c = m0n; m1c = m1n;
  }
  denom += __shfl_xor(denom, 8);
  denom += __shfl_xor(denom, 16);
  denom += __shfl_xor(denom, 32);
  for (int t = 0; t < 16; ++t) {
    acc[t] += __shfl_xor(acc[t], 8);
    acc[t] += __shfl_xor(acc[t], 16);
    acc[t] += __shfl_xor(acc[t], 32);
  }
  float inv = 1.0f / fmaxf(denom, 1e-16f);
  if (sub == 0) {
    unsigned int ov[8];
    for (int t = 0; t < 8; ++t)
      ov[t] = (unsigned int)f2b(acc[2 * t] * inv) | ((unsigned int)f2b(acc[2 * t + 1] * inv) << 16);
    uint4* po = (uint4*)(AGG + (size_t)gw * 128 + cl * 16);
    po[0] = *(uint4*)&ov[0];
    po[1] = *(uint4*)&ov[4];
  }
}

// ---------------- node update (MFMA, in-place HNF), 1-deep reg prefetch ----------------
// LAST=1: node head fused (C holds final HNF bf16 -> 128->32 MFMA -> out_nf).
template <int LAST>
__global__ __launch_bounds__(256)
void node_update(u16* HNF, const u16* nf, const u16* AGG, const u16* WnuT,
                 const u16* b_node, int kc0, int nrows,
                 const u16* WoN, const u16* b_nout, float* out_nf) {
  __shared__ union {
    struct { __align__(16) u16 A[128][40]; __align__(16) u16 B[128][40]; } st;
    u16 C[128][130];
  } sm;
  int blk = blockIdx.x, tid = threadIdx.x;
  int lane = tid & 63, wv = tid >> 6, wr = wv & 1, wc = wv >> 1;
  f32x4 acc[4][4];
  f32x4 zf = {0.f, 0.f, 0.f, 0.f};
  for (int i = 0; i < 4; ++i) for (int j = 0; j < 4; ++j) acc[i][j] = zf;
  int arow = tid >> 1, ahalf = (tid & 1) * 16;
  int r0 = blk * 128;
  int ra = r0 + arow;
  auto asrc = [&](int kc) -> const u16* {
    if (kc < 4) return HNF + (size_t)ra * 128 + kc * 32 + ahalf;
    if (kc == 4) return nf + (size_t)ra * 32 + ahalf;
    return AGG + (size_t)ra * 128 + (kc - 5) * 32 + ahalf;
  };
  uint4 va0 = make_uint4(0, 0, 0, 0), va1 = make_uint4(0, 0, 0, 0), vb0, vb1;
  {
    if (ra < nrows) {
      const uint4* p = (const uint4*)asrc(kc0);
      va0 = p[0]; va1 = p[1];
    }
    const uint4* pb = (const uint4*)(WnuT + arow * 288 + kc0 * 32 + ahalf);
    vb0 = pb[0]; vb1 = pb[1];
  }
  for (int kc = kc0; kc < 9; ++kc) {
    *(uint4*)&sm.st.A[arow][ahalf] = va0;
    *(uint4*)&sm.st.A[arow][ahalf + 8] = va1;
    *(uint4*)&sm.st.B[arow][ahalf] = vb0;
    *(uint4*)&sm.st.B[arow][ahalf + 8] = vb1;
    if (kc < 8) {  // prefetch next chunk
      int kn = kc + 1;
      va0 = make_uint4(0, 0, 0, 0); va1 = make_uint4(0, 0, 0, 0);
      if (ra < nrows) {
        const uint4* p = (const uint4*)asrc(kn);
        va0 = p[0]; va1 = p[1];
      }
      const uint4* pb = (const uint4*)(WnuT + arow * 288 + kn * 32 + ahalf);
      vb0 = pb[0]; vb1 = pb[1];
    }
    __syncthreads();
    int q = lane >> 4, l16 = lane & 15;
    bf16x8 af[4], bfr[4];
    for (int i = 0; i < 4; ++i) af[i] = *(const bf16x8*)&sm.st.A[wr * 64 + i * 16 + l16][q * 8];
    for (int j = 0; j < 4; ++j) bfr[j] = *(const bf16x8*)&sm.st.B[wc * 64 + j * 16 + l16][q * 8];
    for (int i = 0; i < 4; ++i)
      for (int j = 0; j < 4; ++j)
        acc[i][j] = __builtin_amdgcn_mfma_f32_16x16x32_bf16(af[i], bfr[j], acc[i][j], 0, 0, 0);
    __syncthreads();
  }
  int q = lane >> 4, l16 = lane & 15;
  for (int i = 0; i < 4; ++i)
    for (int j = 0; j < 4; ++j) {
      int col = wc * 64 + j * 16 + l16;
      float bb = b2f(b_node[col]);
      for (int rr = 0; rr < 4; ++rr) {
        int row = wr * 64 + i * 16 + q * 4 + rr;
        sm.C[row][col] = f2b(fmaxf(acc[i][j][rr] + bb, 0.f));
      }
    }
  __syncthreads();
  {
    int r = tid >> 1, h = (tid & 1) * 64;
    int rg = r0 + r;
    if (rg < nrows) {
      uint4* po = (uint4*)(HNF + (size_t)rg * 128 + h);
      for (int k = 0; k < 8; ++k) {
        unsigned int a0 = *(const unsigned int*)&sm.C[r][h + k * 8];
        unsigned int a1 = *(const unsigned int*)&sm.C[r][h + k * 8 + 2];
        unsigned int a2 = *(const unsigned int*)&sm.C[r][h + k * 8 + 4];
        unsigned int a3 = *(const unsigned int*)&sm.C[r][h + k * 8 + 6];
        po[k] = make_uint4(a0, a1, a2, a3);
      }
    }
  }
  if constexpr (LAST) {  // fused node head: C holds final HNF bf16
    f32x4 ha[2][2];
    for (int i = 0; i < 2; ++i) for (int j = 0; j < 2; ++j) ha[i][j] = zf;
#pragma unroll
    for (int kc2 = 0; kc2 < 4; ++kc2) {
      bf16x8 af2[2], bf2[2];
      for (int i = 0; i < 2; ++i) {
        unsigned int* ap = (unsigned int*)&af2[i];
        int row = wv * 32 + i * 16 + l16;
        for (int w = 0; w < 4; ++w)
          ap[w] = *(const unsigned int*)&sm.C[row][kc2 * 32 + q * 8 + 2 * w];
      }
      for (int j = 0; j < 2; ++j)
        bf2[j] = *(const bf16x8*)(WoN + (size_t)(j * 16 + l16) * 128 + kc2 * 32 + q * 8);
      for (int i = 0; i < 2; ++i)
        for (int j = 0; j < 2; ++j)
          ha[i][j] = __builtin_amdgcn_mfma_f32_16x16x32_bf16(af2[i], bf2[j], ha[i][j], 0, 0, 0);
    }
    for (int i = 0; i < 2; ++i)
      for (int rr = 0; rr < 4; ++rr) {
        int rowg = r0 + wv * 32 + i * 16 + q * 4 + rr;
        if (rowg < nrows)
          for (int j = 0; j < 2; ++j)
            out_nf[(size_t)rowg * 32 + j * 16 + l16] = ha[i][j][rr] + b2f(b_nout[j * 16 + l16]);
      }
  }
}

extern "C" void kernel_launch(void* const* d_in, const int* in_sizes, int n_in,
                              void* d_out, int out_size, void* d_ws, size_t ws_size,
                              hipStream_t stream) {
  const size_t REQUIRED = 160000000;
  if (ws_size < REQUIRED) return;

  const void* nf_r = d_in[0];
  const void* ef_r = d_in[1];
  const int* src = (const int*)d_in[2];
  const int* dst = (const int*)d_in[3];

  char* ws = (char*)d_ws;
  auto alloc = [&](size_t bytes) {
    char* p = ws;
    ws += (bytes + 255) & ~(size_t)255;
    return p;
  };
  u16* HEF = (u16*)alloc((size_t)GE * 128 * 2);
  u16* HNF = (u16*)alloc((size_t)GN * 128 * 2);
  u16* Xs = (u16*)alloc((size_t)GN * 128 * 2);
  u16* Xd = (u16*)alloc((size_t)GN * 128 * 2);
  float* as_ = (float*)alloc((size_t)GN * 4);
  float* ad_ = (float*)alloc((size_t)GN * 4);
  float* logit = (float*)alloc((size_t)GE * 4);
  int* rowptr = (int*)alloc((size_t)(GN + 1) * 4);
  int* cursor = (int*)alloc((size_t)GN * 4);
  int* eid = (int*)alloc((size_t)GE * 4);
  int* srcs = (int*)alloc((size_t)GE * 4);
  int* dsts = (int*)alloc((size_t)GE * 4);
  u16* WeT = (u16*)alloc(128 * 160 * 2);
  u16* WnpT = (u16*)alloc(256 * 160 * 2);
  u16* WnuT = (u16*)alloc(128 * 288 * 2);
  u16* WoN = (u16*)alloc(32 * 128 * 2);
  u16* WoE = (u16*)alloc(32 * 128 * 2);
  u16* nfc = (u16*)alloc((size_t)GN * 32 * 2);
  u16* efc = (u16*)alloc((size_t)GE * 32 * 2);
  u16* bec = (u16*)alloc(128 * 2);
  u16* Wac = (u16*)alloc(480 * 2);
  u16* bac = (u16*)alloc(2);
  u16* bnc = (u16*)alloc(128 * 2);
  u16* bnoc = (u16*)alloc(32 * 2);
  u16* beoc = (u16*)alloc(32 * 2);
  int* dflag = (int*)alloc(4);
  u16* AGG = Xs;  // overlay: Xs (bf16, 6.4MB) dead after edge stage; AGG consumed
                  // by node_update before next iter's node_proj rewrites Xs

  float* out_nf = (float*)d_out;
  float* out_ef = (float*)d_out + (size_t)GN * 32;

  detect_dtype<<<1, 64, 0, stream>>>(nf_r, dflag);
  // CSR build first (gathers depend on eid)
  hipMemsetAsync(cursor, 0, (size_t)GN * 4, stream);
  hist_kernel<<<1563, 256, 0, stream>>>(dst, cursor, GE);
  scan_kernel<<<1, 1024, 0, stream>>>(cursor, rowptr, GN);
  fill_kernel<<<1563, 256, 0, stream>>>(src, dst, cursor, eid, srcs, dsts, GE);

  gather_ef<<<6250, 256, 0, stream>>>(ef_r, eid, efc, dflag);
  prep_weights<<<128, 256, 0, stream>>>(d_in[4], d_in[8], d_in[6], d_in[10], d_in[12],
                                        d_in[5], d_in[7], d_in[9], d_in[11], d_in[13], nf_r,
                                        WeT, WnpT, WnuT, WoN, WoE,
                                        Wac, bec, bac, bnc, bnoc, beoc, nfc, dflag);

  for (int iter = 0; iter < 3; ++iter) {
    int kc0 = (iter == 0) ? 4 : 0;
    dim3 npgrid(NODE_BLKS, 2);
    node_proj<<<npgrid, 256, 0, stream>>>(HNF, nfc, WnpT, Wac, Xs, Xd, as_, ad_, kc0, GN);
    if (iter == 0)
      edge_fused<4, 0><<<EDGE_BLKS, 256, 0, stream>>>(HEF, efc, WeT, Wac, bec, bac, srcs, dsts,
                                                      Xs, Xd, as_, ad_, logit, WoE, beoc, eid, out_ef);
    else if (iter == 1)
      edge_fused<0, 0><<<EDGE_BLKS, 256, 0, stream>>>(HEF, efc, WeT, Wac, bec, bac, srcs, dsts,
                                                      Xs, Xd, as_, ad_, logit, WoE, beoc, eid, out_ef);
    else
      edge_fused<0, 1><<<EDGE_BLKS, 256, 0, stream>>>(HEF, efc, WeT, Wac, bec, bac, srcs, dsts,
                                                      Xs, Xd, as_, ad_, logit, WoE, beoc, eid, out_ef);
    aggregate<<<(GN + 3) / 4, 256, 0, stream>>>(rowptr, logit, HEF, AGG, GN);
    if (iter < 2)
      node_update<0><<<NODE_BLKS, 256, 0, stream>>>(HNF, nfc, AGG, WnuT, bnc, kc0, GN,
                                                    WoN, bnoc, out_nf);
    else
      node_update<1><<<NODE_BLKS, 256, 0, stream>>>(HNF, nfc, AGG, WnuT, bnc, kc0, GN,
                                                    WoN, bnoc, out_nf);
  }
}

// Round 11
// 592.855 us; speedup vs baseline: 1.0178x; 1.0178x over previous
//
#include <hip/hip_runtime.h>

// IJGNN attention-MPNN, 3 iterations. fp32 in/out, bf16 internal.
// Edges processed in dst-sorted (CSR) order; edge head scatters back via eid.
// This rev: restore round-7 measured-best config (593.5us):
//  - edge_fused LAST epilogue back to SCALAR out_ef scatter (r10 A/B: the
//    vectorized restage cost +2.5us -- extra barriers outweighed store count).
//  - prep_weights keeps the nf-fold (-1 launch) but launches with 784 blocks
//    (r10's 128-block fold left half the CUs idle on the 800K-elem convert).
//  - no XCD swizzle (r9/r10 A/B: neutral-to-negative).

#define GN 25000
#define GE 400000
#define NODE_BLKS 196    // ceil(GN/128)
#define EDGE_BLKS 6250   // GE/64 exact (edge_fused tiles)

typedef unsigned short u16;
typedef __attribute__((ext_vector_type(8))) short bf16x8;
typedef __attribute__((ext_vector_type(4))) float f32x4;

__device__ inline float b2f(u16 v) {
  union { unsigned int u; float f; } x; x.u = ((unsigned int)v) << 16; return x.f;
}
__device__ inline u16 f2b(float f) {
  union { float f; unsigned int u; } x; x.f = f;
  unsigned int u = x.u;
  u += 0x7fffu + ((u >> 16) & 1u);
  return (u16)(u >> 16);
}

// ---------------- dtype probe ----------------
__global__ void detect_dtype(const void* nf, int* flag) {
  if (blockIdx.x == 0 && threadIdx.x == 0) {
    const u16* p = (const u16*)nf;
    int cnt = 0;
    for (int i = 0; i < 512; i += 2) {
      int e = (p[i] >> 7) & 0xFF;
      if (e >= 0x70 && e <= 0x85) cnt++;
    }
    *flag = (cnt < 128) ? 1 : 0;
  }
}

// gather ef rows into dst-sorted order (+convert), 16B per thread
__global__ void gather_ef(const void* ef, const int* eid, u16* efc, const int* flag) {
  int f32 = *flag;
  long idx = (long)blockIdx.x * blockDim.x + threadIdx.x;
  long ntot = (long)GE * 4;  // 8-col groups
  if (idx >= ntot) return;
  long j = idx >> 2;
  int g = (int)(idx & 3) * 8;
  long e = eid[j];
  uint4 out;
  if (f32) {
    const float* pf = (const float*)ef + e * 32 + g;
    float4 a = ((const float4*)pf)[0];
    float4 b = ((const float4*)pf)[1];
    unsigned int* ov = (unsigned int*)&out;
    ov[0] = (unsigned int)f2b(a.x) | ((unsigned int)f2b(a.y) << 16);
    ov[1] = (unsigned int)f2b(a.z) | ((unsigned int)f2b(a.w) << 16);
    ov[2] = (unsigned int)f2b(b.x) | ((unsigned int)f2b(b.y) << 16);
    ov[3] = (unsigned int)f2b(b.z) | ((unsigned int)f2b(b.w) << 16);
  } else {
    out = *(const uint4*)((const u16*)ef + e * 32 + g);
  }
  *(uint4*)(efc + j * 32 + g) = out;
}

// ---------------- weight prep + nf convert, one launch (784 blocks) ----------------
__global__ void prep_weights(const void* We, const void* Wn, const void* Wa,
                             const void* Won, const void* Woe,
                             const void* be, const void* ba, const void* bn,
                             const void* bno, const void* beo, const void* nf,
                             u16* WeT, u16* WnpT, u16* WnuT, u16* WoN, u16* WoE,
                             u16* Wac, u16* bec, u16* bac, u16* bnc, u16* bnoc, u16* beoc,
                             u16* nfc, const int* flag) {
  int f32 = *flag;
  auto ld = [&](const void* p, long i) -> u16 {
    return f32 ? f2b(((const float*)p)[i]) : ((const u16*)p)[i];
  };
  int tid = blockIdx.x * blockDim.x + threadIdx.x;
  int nt = gridDim.x * blockDim.x;
  for (long i = tid; i < (long)GN * 32; i += nt) nfc[i] = ld(nf, i);
  for (int i = tid; i < 128 * 160; i += nt) { int n = i / 160, k = i % 160; WeT[i] = ld(We, (long)(320 + k) * 128 + n); }
  for (int i = tid; i < 256 * 160; i += nt) {
    int c = i / 160, k = i % 160;
    WnpT[i] = (c < 128) ? ld(We, (long)k * 128 + c) : ld(We, (long)(160 + k) * 128 + (c - 128));
  }
  for (int i = tid; i < 128 * 288; i += nt) { int c = i / 288, k = i % 288; WnuT[i] = ld(Wn, (long)k * 128 + c); }
  for (int i = tid; i < 32 * 128; i += nt) {
    int c = i / 128, k = i % 128;
    WoN[i] = ld(Won, (long)k * 32 + c);
    WoE[i] = ld(Woe, (long)k * 32 + c);
  }
  for (int i = tid; i < 480; i += nt) Wac[i] = ld(Wa, i);
  for (int i = tid; i < 128; i += nt) { bec[i] = ld(be, i); bnc[i] = ld(bn, i); }
  for (int i = tid; i < 32; i += nt) { bnoc[i] = ld(bno, i); beoc[i] = ld(beo, i); }
  if (tid == 0) bac[0] = ld(ba, 0);
}

// ---------------- CSR build ----------------
__global__ void hist_kernel(const int* dst, int* counts, int n) {
  for (int e = blockIdx.x * blockDim.x + threadIdx.x; e < n; e += gridDim.x * blockDim.x)
    atomicAdd(&counts[dst[e]], 1);
}

__global__ __launch_bounds__(1024) void scan_kernel(int* cursor, int* rowptr, int n) {
  __shared__ int part[1024];
  int t = threadIdx.x;
  int per = (n + 1023) / 1024;
  int lo = t * per;
  int hi = lo + per; if (hi > n) hi = n;
  if (lo > n) lo = n;
  int s = 0;
  for (int i = lo; i < hi; ++i) s += cursor[i];
  part[t] = s;
  __syncthreads();
  for (int off = 1; off < 1024; off <<= 1) {
    int v = (t >= off) ? part[t - off] : 0;
    __syncthreads();
    part[t] += v;
    __syncthreads();
  }
  int run = (t > 0) ? part[t - 1] : 0;
  for (int i = lo; i < hi; ++i) {
    int c = cursor[i];
    cursor[i] = run;
    rowptr[i + 1] = run + c;
    run += c;
  }
  if (t == 0) rowptr[0] = 0;
}

// fill CSR order + gather src/dst meta in the same pass
__global__ void fill_kernel(const int* src, const int* dst, int* cursor, int* eid,
                            int* srcs, int* dsts, int n) {
  for (int e = blockIdx.x * blockDim.x + threadIdx.x; e < n; e += gridDim.x * blockDim.x) {
    int d = dst[e];
    int p = atomicAdd(&cursor[d], 1);
    eid[p] = e;
    srcs[p] = src[e];
    dsts[p] = d;
  }
}

// ---------------- node projections (MFMA): Xs/Xd [N,128] bf16, as/ad [N] fp32 ----------------
__global__ __launch_bounds__(256)
void node_proj(const u16* HNF, const u16* nf, const u16* WnpT, const u16* W_attn,
               u16* Xs, u16* Xd, float* as_, float* ad_, int kc0, int nrows) {
  __shared__ union {
    struct { __align__(16) u16 A[128][40]; __align__(16) u16 B[128][40]; } st;
    u16 C[128][130];  // bf16 transpose buffer (final values; no extra rounding)
  } sm;
  __shared__ float dotbuf[128][2];
  int sel = blockIdx.y, blk = blockIdx.x, tid = threadIdx.x;
  int lane = tid & 63, wv = tid >> 6, wr = wv & 1, wc = wv >> 1;
  const u16* BT = WnpT + sel * 128 * 160;
  u16* OUT = sel ? Xd : Xs;
  float* AOUT = sel ? ad_ : as_;
  const u16* wa = W_attn + sel * 160;
  f32x4 acc[4][4];
  f32x4 zf = {0.f, 0.f, 0.f, 0.f};
  for (int i = 0; i < 4; ++i) for (int j = 0; j < 4; ++j) acc[i][j] = zf;
  float dp = 0.f;
  int arow = tid >> 1, ahalf = (tid & 1) * 16;
  int r0 = blk * 128;
  int ra = r0 + arow;
  uint4 va0 = make_uint4(0, 0, 0, 0), va1 = make_uint4(0, 0, 0, 0), vb0, vb1;
  {
    if (ra < nrows) {
      const uint4* p = (kc0 < 4) ? (const uint4*)(HNF + (size_t)ra * 128 + kc0 * 32 + ahalf)
                                 : (const uint4*)(nf + (size_t)ra * 32 + ahalf);
      va0 = p[0]; va1 = p[1];
    }
    const uint4* pb = (const uint4*)(BT + arow * 160 + kc0 * 32 + ahalf);
    vb0 = pb[0]; vb1 = pb[1];
  }
  for (int kc = kc0; kc < 5; ++kc) {
    *(uint4*)&sm.st.A[arow][ahalf] = va0;
    *(uint4*)&sm.st.A[arow][ahalf + 8] = va1;
    *(uint4*)&sm.st.B[arow][ahalf] = vb0;
    *(uint4*)&sm.st.B[arow][ahalf + 8] = vb1;
    if (kc < 4) {  // prefetch next chunk
      int kn = kc + 1;
      va0 = make_uint4(0, 0, 0, 0); va1 = make_uint4(0, 0, 0, 0);
      if (ra < nrows) {
        const uint4* p = (kn < 4) ? (const uint4*)(HNF + (size_t)ra * 128 + kn * 32 + ahalf)
                                  : (const uint4*)(nf + (size_t)ra * 32 + ahalf);
        va0 = p[0]; va1 = p[1];
      }
      const uint4* pb = (const uint4*)(BT + arow * 160 + kn * 32 + ahalf);
      vb0 = pb[0]; vb1 = pb[1];
    }
    __syncthreads();
    {
      float s = 0.f;
      for (int j = 0; j < 16; ++j) s += b2f(sm.st.A[arow][ahalf + j]) * b2f(wa[kc * 32 + ahalf + j]);
      dp += s;
    }
    int q = lane >> 4, l16 = lane & 15;
    bf16x8 af[4], bfr[4];
    for (int i = 0; i < 4; ++i) af[i] = *(const bf16x8*)&sm.st.A[wr * 64 + i * 16 + l16][q * 8];
    for (int j = 0; j < 4; ++j) bfr[j] = *(const bf16x8*)&sm.st.B[wc * 64 + j * 16 + l16][q * 8];
    for (int i = 0; i < 4; ++i)
      for (int j = 0; j < 4; ++j)
        acc[i][j] = __builtin_amdgcn_mfma_f32_16x16x32_bf16(af[i], bfr[j], acc[i][j], 0, 0, 0);
    __syncthreads();
  }
  dotbuf[arow][tid & 1] = dp;
  // scatter acc -> LDS transpose buffer (overlays staging; K-loop is done)
  {
    int q = lane >> 4, l16 = lane & 15;
    for (int i = 0; i < 4; ++i)
      for (int j = 0; j < 4; ++j) {
        int col = wc * 64 + j * 16 + l16;
        for (int rr = 0; rr < 4; ++rr) {
          int row = wr * 64 + i * 16 + q * 4 + rr;
          sm.C[row][col] = f2b(acc[i][j][rr]);
        }
      }
  }
  __syncthreads();
  if (tid < 128) {
    int r = r0 + tid;
    if (r < nrows) AOUT[r] = dotbuf[tid][0] + dotbuf[tid][1];
  }
  // vectorized store: each thread owns one row-half (64 cols = 8x dwordx4)
  {
    int r = tid >> 1, h = (tid & 1) * 64;
    int rg = r0 + r;
    if (rg < nrows) {
      uint4* po = (uint4*)(OUT + (size_t)rg * 128 + h);
      for (int k = 0; k < 8; ++k) {
        unsigned int a0 = *(const unsigned int*)&sm.C[r][h + k * 8];
        unsigned int a1 = *(const unsigned int*)&sm.C[r][h + k * 8 + 2];
        unsigned int a2 = *(const unsigned int*)&sm.C[r][h + k * 8 + 4];
        unsigned int a3 = *(const unsigned int*)&sm.C[r][h + k * 8 + 6];
        po[k] = make_uint4(a0, a1, a2, a3);
      }
    }
  }
}

// ---------------- edge stage: 64-edge tiles, A dbuf LDS, B frags from L2 (ping-pong) ----------------
// Round-7 body exactly (best measured). LAST=1: fused edge head with SCALAR
// eid-scattered out_ef writes (measured faster than vectorized restage).
template <int KC0, int LAST>
__global__ __launch_bounds__(256, 4)
void edge_fused(u16* HEF, const u16* ef, const u16* WeT, const u16* W_attn,
                const u16* b_edge, const u16* b_attn, const int* srcs, const int* dsts,
                const u16* Xs, const u16* Xd, const float* as_, const float* ad_,
                float* logit, const u16* WoE, const u16* b_eout, const int* eid,
                float* out_ef) {
  __shared__ union {
    __align__(16) u16 A[2][64][40];  // double-buffered A chunk (10.2KB)
    float C[64][65];                 // epilogue transpose (16.6KB); bank spread
  } sm;
  __shared__ float dotbuf[64];
  __shared__ __align__(16) u16 Mt[LAST ? 64 : 1][136];  // bf16 M tile for head GEMM
  int blk = blockIdx.x, tid = threadIdx.x;
  int lane = tid & 63, wv = tid >> 6, wr = wv & 1, wc = wv >> 1;
  int q = lane >> 4, l16 = lane & 15;
  f32x4 acc[2][4];
  f32x4 zf = {0.f, 0.f, 0.f, 0.f};
  for (int i = 0; i < 2; ++i) for (int j = 0; j < 4; ++j) acc[i][j] = zf;
  float dp[2] = {0.f, 0.f};
  long e0 = (long)blk * 64;
  long ea = e0 + (tid >> 2);
  int qp = (tid & 3) * 8;  // A col offset (u16 units), 16B per thread
  const u16* wa = W_attn + 320;

  uint4 va = (KC0 < 4) ? *(const uint4*)(HEF + ea * 128 + KC0 * 32 + qp)
                       : *(const uint4*)(ef + ea * 32 + qp);
  bf16x8 bfp[2][4];
#pragma unroll
  for (int j = 0; j < 4; ++j)
    bfp[KC0 & 1][j] = *(const bf16x8*)(WeT + (size_t)(wc * 64 + j * 16 + l16) * 160 + KC0 * 32 + q * 8);

#pragma unroll
  for (int kc = KC0; kc < 5; ++kc) {
    int buf = kc & 1;
    *(uint4*)&sm.A[buf][tid >> 2][qp] = va;
    if (kc < 4) {  // issue next-chunk loads; latency hides under barrier+MFMA
      va = (kc + 1 < 4) ? *(const uint4*)(HEF + ea * 128 + (kc + 1) * 32 + qp)
                        : *(const uint4*)(ef + ea * 32 + qp);
#pragma unroll
      for (int j = 0; j < 4; ++j)
        bfp[(kc + 1) & 1][j] = *(const bf16x8*)(WeT + (size_t)(wc * 64 + j * 16 + l16) * 160 + (kc + 1) * 32 + q * 8);
    }
    __syncthreads();
    bf16x8 af[2];
    for (int i = 0; i < 2; ++i) af[i] = *(const bf16x8*)&sm.A[buf][wr * 32 + i * 16 + l16][q * 8];
    if (wc == 0) {
      bf16x8 wv8 = *(const bf16x8*)&wa[kc * 32 + q * 8];
      float wf[8];
      for (int j = 0; j < 8; ++j) wf[j] = b2f((u16)wv8[j]);
      for (int i = 0; i < 2; ++i)
        for (int j = 0; j < 8; ++j) dp[i] += b2f((u16)af[i][j]) * wf[j];
    }
    for (int i = 0; i < 2; ++i)
      for (int j = 0; j < 4; ++j)
        acc[i][j] = __builtin_amdgcn_mfma_f32_16x16x32_bf16(af[i], bfp[buf][j], acc[i][j], 0, 0, 0);
  }
  if (wc == 0) {
    for (int i = 0; i < 2; ++i) {
      dp[i] += __shfl_xor(dp[i], 16);
      dp[i] += __shfl_xor(dp[i], 32);
    }
    if (q == 0)
      for (int i = 0; i < 2; ++i) dotbuf[wr * 32 + i * 16 + l16] = dp[i];
  }
  int r = tid >> 2, qh = tid & 3;  // each thread: one edge row, 16 cols/pass
  long e = e0 + r;
  int s = srcs[e], d = dsts[e];
#pragma unroll
  for (int p = 0; p < 2; ++p) {
    int cb = p * 64 + qh * 16;
    // issue vector gathers early: latency hides under barrier + LDS scatter
    const uint4* ps = (const uint4*)(Xs + (size_t)s * 128 + cb);
    const uint4* pd = (const uint4*)(Xd + (size_t)d * 128 + cb);
    uint4 gs0 = ps[0], gs1 = ps[1], gd0 = pd[0], gd1 = pd[1];
    // p=0: wait for all waves' last A-reads + dotbuf writes before overlaying C
    // p=1: wait for pass-0 C reads before rewriting C
    __syncthreads();
    if (wc == p) {  // this wave pair's acc covers cols [p*64, p*64+64)
      for (int i = 0; i < 2; ++i)
        for (int j = 0; j < 4; ++j) {
          int col = j * 16 + l16;
          float bb = b2f(b_edge[p * 64 + col]);
          for (int rr = 0; rr < 4; ++rr)
            sm.C[wr * 32 + i * 16 + q * 4 + rr][col] = acc[i][j][rr] + bb;
        }
    }
    __syncthreads();
    if (p == 0 && tid < 64) {
      long ee = e0 + tid;
      logit[ee] = dotbuf[tid] + as_[srcs[ee]] + ad_[dsts[ee]] + b2f(b_attn[0]);
    }
    unsigned int us[8], ud[8];
    *(uint4*)&us[0] = gs0; *(uint4*)&us[4] = gs1;
    *(uint4*)&ud[0] = gd0; *(uint4*)&ud[4] = gd1;
    unsigned int ov[8];
    for (int w = 0; w < 8; ++w) {
      float c0 = sm.C[r][qh * 16 + 2 * w];
      float c1 = sm.C[r][qh * 16 + 2 * w + 1];
      float v0 = c0 + b2f((u16)(us[w] & 0xffffu)) + b2f((u16)(ud[w] & 0xffffu));
      float v1 = c1 + b2f((u16)(us[w] >> 16)) + b2f((u16)(ud[w] >> 16));
      ov[w] = (unsigned int)f2b(fmaxf(v0, 0.f)) | ((unsigned int)f2b(fmaxf(v1, 0.f)) << 16);
    }
    if constexpr (LAST) {  // stash M for the fused head GEMM (same bf16 bits)
      *(uint4*)&Mt[r][cb] = *(uint4*)&ov[0];
      *(uint4*)&Mt[r][cb + 8] = *(uint4*)&ov[4];
    }
    uint4* po = (uint4*)(HEF + e * 128 + cb);
    po[0] = *(uint4*)&ov[0];
    po[1] = *(uint4*)&ov[4];
  }
  if constexpr (LAST) {
    __syncthreads();  // all Mt writes visible
    f32x4 ha0 = zf, ha1 = zf;  // wave wv: out rows [wv*16, +16), 32 cols
#pragma unroll
    for (int kc2 = 0; kc2 < 4; ++kc2) {
      bf16x8 af2 = *(const bf16x8*)&Mt[wv * 16 + l16][kc2 * 32 + q * 8];
      bf16x8 b0 = *(const bf16x8*)(WoE + (size_t)l16 * 128 + kc2 * 32 + q * 8);
      bf16x8 b1 = *(const bf16x8*)(WoE + (size_t)(16 + l16) * 128 + kc2 * 32 + q * 8);
      ha0 = __builtin_amdgcn_mfma_f32_16x16x32_bf16(af2, b0, ha0, 0, 0, 0);
      ha1 = __builtin_amdgcn_mfma_f32_16x16x32_bf16(af2, b1, ha1, 0, 0, 0);
    }
    float bb0 = b2f(b_eout[l16]), bb1 = b2f(b_eout[16 + l16]);
    for (int rr = 0; rr < 4; ++rr) {
      long ee = e0 + wv * 16 + q * 4 + rr;
      long ro = eid[ee];
      out_ef[ro * 32 + l16] = ha0[rr] + bb0;
      out_ef[ro * 32 + 16 + l16] = ha1[rr] + bb1;
    }
  }
}

// ---------------- per-dst softmax + aggregation ----------------
__global__ __launch_bounds__(256)
void aggregate(const int* rowptr, const float* logit, const u16* M, u16* AGG, int nrows) {
  int gw = (blockIdx.x * blockDim.x + threadIdx.x) >> 6;
  int lane = threadIdx.x & 63;
  if (gw >= nrows) return;
  int beg = rowptr[gw], end = rowptr[gw + 1];
  int sub = lane >> 3, cl = lane & 7;
  float mx = -1e30f;
  for (int j = beg + lane; j < end; j += 64) mx = fmaxf(mx, logit[j]);
  for (int off = 32; off > 0; off >>= 1) mx = fmaxf(mx, __shfl_xor(mx, off));
  float acc[16];
  for (int t = 0; t < 16; ++t) acc[t] = 0.f;
  float denom = 0.f;
  float wc = 0.f;
  uint4 m0c = make_uint4(0, 0, 0, 0), m1c = make_uint4(0, 0, 0, 0);
  {
    int j = beg + sub;
    if (j < end) {
      wc = __expf(logit[j] - mx);
      const uint4* mp = (const uint4*)(M + (size_t)j * 128 + cl * 16);
      m0c = mp[0]; m1c = mp[1];
    }
  }
  for (int j0 = beg; j0 < end; j0 += 8) {
    float wn = 0.f;
    uint4 m0n = make_uint4(0, 0, 0, 0), m1n = make_uint4(0, 0, 0, 0);
    int jn = j0 + 8 + sub;
    if (jn < end) {
      wn = __expf(logit[jn] - mx);
      const uint4* mp = (const uint4*)(M + (size_t)jn * 128 + cl * 16);
      m0n = mp[0]; m1n = mp[1];
    }
    denom += wc;
    const unsigned int* mw0 = (const unsigned int*)&m0c;
    const unsigned int* mw1 = (const unsigned int*)&m1c;
    for (int t = 0; t < 4; ++t) {
      acc[2 * t]     += wc * b2f((u16)(mw0[t] & 0xffffu));
      acc[2 * t + 1] += wc * b2f((u16)(mw0[t] >> 16));
      acc[8 + 2 * t]     += wc * b2f((u16)(mw1[t] & 0xffffu));
      acc[8 + 2 * t + 1] += wc * b2f((u16)(mw1[t] >> 16));
    }
    wc = wn; m0c = m0n; m1c = m1n;
  }
  denom += __shfl_xor(denom, 8);
  denom += __shfl_xor(denom, 16);
  denom += __shfl_xor(denom, 32);
  for (int t = 0; t < 16; ++t) {
    acc[t] += __shfl_xor(acc[t], 8);
    acc[t] += __shfl_xor(acc[t], 16);
    acc[t] += __shfl_xor(acc[t], 32);
  }
  float inv = 1.0f / fmaxf(denom, 1e-16f);
  if (sub == 0) {
    unsigned int ov[8];
    for (int t = 0; t < 8; ++t)
      ov[t] = (unsigned int)f2b(acc[2 * t] * inv) | ((unsigned int)f2b(acc[2 * t + 1] * inv) << 16);
    uint4* po = (uint4*)(AGG + (size_t)gw * 128 + cl * 16);
    po[0] = *(uint4*)&ov[0];
    po[1] = *(uint4*)&ov[4];
  }
}

// ---------------- node update (MFMA, in-place HNF), 1-deep reg prefetch ----------------
// LAST=1: node head fused (C holds final HNF bf16 -> 128->32 MFMA -> out_nf).
template <int LAST>
__global__ __launch_bounds__(256)
void node_update(u16* HNF, const u16* nf, const u16* AGG, const u16* WnuT,
                 const u16* b_node, int kc0, int nrows,
                 const u16* WoN, const u16* b_nout, float* out_nf) {
  __shared__ union {
    struct { __align__(16) u16 A[128][40]; __align__(16) u16 B[128][40]; } st;
    u16 C[128][130];
  } sm;
  int blk = blockIdx.x, tid = threadIdx.x;
  int lane = tid & 63, wv = tid >> 6, wr = wv & 1, wc = wv >> 1;
  f32x4 acc[4][4];
  f32x4 zf = {0.f, 0.f, 0.f, 0.f};
  for (int i = 0; i < 4; ++i) for (int j = 0; j < 4; ++j) acc[i][j] = zf;
  int arow = tid >> 1, ahalf = (tid & 1) * 16;
  int r0 = blk * 128;
  int ra = r0 + arow;
  auto asrc = [&](int kc) -> const u16* {
    if (kc < 4) return HNF + (size_t)ra * 128 + kc * 32 + ahalf;
    if (kc == 4) return nf + (size_t)ra * 32 + ahalf;
    return AGG + (size_t)ra * 128 + (kc - 5) * 32 + ahalf;
  };
  uint4 va0 = make_uint4(0, 0, 0, 0), va1 = make_uint4(0, 0, 0, 0), vb0, vb1;
  {
    if (ra < nrows) {
      const uint4* p = (const uint4*)asrc(kc0);
      va0 = p[0]; va1 = p[1];
    }
    const uint4* pb = (const uint4*)(WnuT + arow * 288 + kc0 * 32 + ahalf);
    vb0 = pb[0]; vb1 = pb[1];
  }
  for (int kc = kc0; kc < 9; ++kc) {
    *(uint4*)&sm.st.A[arow][ahalf] = va0;
    *(uint4*)&sm.st.A[arow][ahalf + 8] = va1;
    *(uint4*)&sm.st.B[arow][ahalf] = vb0;
    *(uint4*)&sm.st.B[arow][ahalf + 8] = vb1;
    if (kc < 8) {  // prefetch next chunk
      int kn = kc + 1;
      va0 = make_uint4(0, 0, 0, 0); va1 = make_uint4(0, 0, 0, 0);
      if (ra < nrows) {
        const uint4* p = (const uint4*)asrc(kn);
        va0 = p[0]; va1 = p[1];
      }
      const uint4* pb = (const uint4*)(WnuT + arow * 288 + kn * 32 + ahalf);
      vb0 = pb[0]; vb1 = pb[1];
    }
    __syncthreads();
    int q = lane >> 4, l16 = lane & 15;
    bf16x8 af[4], bfr[4];
    for (int i = 0; i < 4; ++i) af[i] = *(const bf16x8*)&sm.st.A[wr * 64 + i * 16 + l16][q * 8];
    for (int j = 0; j < 4; ++j) bfr[j] = *(const bf16x8*)&sm.st.B[wc * 64 + j * 16 + l16][q * 8];
    for (int i = 0; i < 4; ++i)
      for (int j = 0; j < 4; ++j)
        acc[i][j] = __builtin_amdgcn_mfma_f32_16x16x32_bf16(af[i], bfr[j], acc[i][j], 0, 0, 0);
    __syncthreads();
  }
  int q = lane >> 4, l16 = lane & 15;
  for (int i = 0; i < 4; ++i)
    for (int j = 0; j < 4; ++j) {
      int col = wc * 64 + j * 16 + l16;
      float bb = b2f(b_node[col]);
      for (int rr = 0; rr < 4; ++rr) {
        int row = wr * 64 + i * 16 + q * 4 + rr;
        sm.C[row][col] = f2b(fmaxf(acc[i][j][rr] + bb, 0.f));
      }
    }
  __syncthreads();
  {
    int r = tid >> 1, h = (tid & 1) * 64;
    int rg = r0 + r;
    if (rg < nrows) {
      uint4* po = (uint4*)(HNF + (size_t)rg * 128 + h);
      for (int k = 0; k < 8; ++k) {
        unsigned int a0 = *(const unsigned int*)&sm.C[r][h + k * 8];
        unsigned int a1 = *(const unsigned int*)&sm.C[r][h + k * 8 + 2];
        unsigned int a2 = *(const unsigned int*)&sm.C[r][h + k * 8 + 4];
        unsigned int a3 = *(const unsigned int*)&sm.C[r][h + k * 8 + 6];
        po[k] = make_uint4(a0, a1, a2, a3);
      }
    }
  }
  if constexpr (LAST) {  // fused node head: C holds final HNF bf16
    f32x4 ha[2][2];
    for (int i = 0; i < 2; ++i) for (int j = 0; j < 2; ++j) ha[i][j] = zf;
#pragma unroll
    for (int kc2 = 0; kc2 < 4; ++kc2) {
      bf16x8 af2[2], bf2[2];
      for (int i = 0; i < 2; ++i) {
        unsigned int* ap = (unsigned int*)&af2[i];
        int row = wv * 32 + i * 16 + l16;
        for (int w = 0; w < 4; ++w)
          ap[w] = *(const unsigned int*)&sm.C[row][kc2 * 32 + q * 8 + 2 * w];
      }
      for (int j = 0; j < 2; ++j)
        bf2[j] = *(const bf16x8*)(WoN + (size_t)(j * 16 + l16) * 128 + kc2 * 32 + q * 8);
      for (int i = 0; i < 2; ++i)
        for (int j = 0; j < 2; ++j)
          ha[i][j] = __builtin_amdgcn_mfma_f32_16x16x32_bf16(af2[i], bf2[j], ha[i][j], 0, 0, 0);
    }
    for (int i = 0; i < 2; ++i)
      for (int rr = 0; rr < 4; ++rr) {
        int rowg = r0 + wv * 32 + i * 16 + q * 4 + rr;
        if (rowg < nrows)
          for (int j = 0; j < 2; ++j)
            out_nf[(size_t)rowg * 32 + j * 16 + l16] = ha[i][j][rr] + b2f(b_nout[j * 16 + l16]);
      }
  }
}

extern "C" void kernel_launch(void* const* d_in, const int* in_sizes, int n_in,
                              void* d_out, int out_size, void* d_ws, size_t ws_size,
                              hipStream_t stream) {
  const size_t REQUIRED = 160000000;
  if (ws_size < REQUIRED) return;

  const void* nf_r = d_in[0];
  const void* ef_r = d_in[1];
  const int* src = (const int*)d_in[2];
  const int* dst = (const int*)d_in[3];

  char* ws = (char*)d_ws;
  auto alloc = [&](size_t bytes) {
    char* p = ws;
    ws += (bytes + 255) & ~(size_t)255;
    return p;
  };
  u16* HEF = (u16*)alloc((size_t)GE * 128 * 2);
  u16* HNF = (u16*)alloc((size_t)GN * 128 * 2);
  u16* Xs = (u16*)alloc((size_t)GN * 128 * 2);
  u16* Xd = (u16*)alloc((size_t)GN * 128 * 2);
  float* as_ = (float*)alloc((size_t)GN * 4);
  float* ad_ = (float*)alloc((size_t)GN * 4);
  float* logit = (float*)alloc((size_t)GE * 4);
  int* rowptr = (int*)alloc((size_t)(GN + 1) * 4);
  int* cursor = (int*)alloc((size_t)GN * 4);
  int* eid = (int*)alloc((size_t)GE * 4);
  int* srcs = (int*)alloc((size_t)GE * 4);
  int* dsts = (int*)alloc((size_t)GE * 4);
  u16* WeT = (u16*)alloc(128 * 160 * 2);
  u16* WnpT = (u16*)alloc(256 * 160 * 2);
  u16* WnuT = (u16*)alloc(128 * 288 * 2);
  u16* WoN = (u16*)alloc(32 * 128 * 2);
  u16* WoE = (u16*)alloc(32 * 128 * 2);
  u16* nfc = (u16*)alloc((size_t)GN * 32 * 2);
  u16* efc = (u16*)alloc((size_t)GE * 32 * 2);
  u16* bec = (u16*)alloc(128 * 2);
  u16* Wac = (u16*)alloc(480 * 2);
  u16* bac = (u16*)alloc(2);
  u16* bnc = (u16*)alloc(128 * 2);
  u16* bnoc = (u16*)alloc(32 * 2);
  u16* beoc = (u16*)alloc(32 * 2);
  int* dflag = (int*)alloc(4);
  u16* AGG = Xs;  // overlay: Xs (bf16, 6.4MB) dead after edge stage; AGG consumed
                  // by node_update before next iter's node_proj rewrites Xs

  float* out_nf = (float*)d_out;
  float* out_ef = (float*)d_out + (size_t)GN * 32;

  detect_dtype<<<1, 64, 0, stream>>>(nf_r, dflag);
  // CSR build first (gathers depend on eid)
  hipMemsetAsync(cursor, 0, (size_t)GN * 4, stream);
  hist_kernel<<<1563, 256, 0, stream>>>(dst, cursor, GE);
  scan_kernel<<<1, 1024, 0, stream>>>(cursor, rowptr, GN);
  fill_kernel<<<1563, 256, 0, stream>>>(src, dst, cursor, eid, srcs, dsts, GE);

  gather_ef<<<6250, 256, 0, stream>>>(ef_r, eid, efc, dflag);
  prep_weights<<<784, 256, 0, stream>>>(d_in[4], d_in[8], d_in[6], d_in[10], d_in[12],
                                        d_in[5], d_in[7], d_in[9], d_in[11], d_in[13], nf_r,
                                        WeT, WnpT, WnuT, WoN, WoE,
                                        Wac, bec, bac, bnc, bnoc, beoc, nfc, dflag);

  for (int iter = 0; iter < 3; ++iter) {
    int kc0 = (iter == 0) ? 4 : 0;
    dim3 npgrid(NODE_BLKS, 2);
    node_proj<<<npgrid, 256, 0, stream>>>(HNF, nfc, WnpT, Wac, Xs, Xd, as_, ad_, kc0, GN);
    if (iter == 0)
      edge_fused<4, 0><<<EDGE_BLKS, 256, 0, stream>>>(HEF, efc, WeT, Wac, bec, bac, srcs, dsts,
                                                      Xs, Xd, as_, ad_, logit, WoE, beoc, eid, out_ef);
    else if (iter == 1)
      edge_fused<0, 0><<<EDGE_BLKS, 256, 0, stream>>>(HEF, efc, WeT, Wac, bec, bac, srcs, dsts,
                                                      Xs, Xd, as_, ad_, logit, WoE, beoc, eid, out_ef);
    else
      edge_fused<0, 1><<<EDGE_BLKS, 256, 0, stream>>>(HEF, efc, WeT, Wac, bec, bac, srcs, dsts,
                                                      Xs, Xd, as_, ad_, logit, WoE, beoc, eid, out_ef);
    aggregate<<<(GN + 3) / 4, 256, 0, stream>>>(rowptr, logit, HEF, AGG, GN);
    if (iter < 2)
      node_update<0><<<NODE_BLKS, 256, 0, stream>>>(HNF, nfc, AGG, WnuT, bnc, kc0, GN,
                                                    WoN, bnoc, out_nf);
    else
      node_update<1><<<NODE_BLKS, 256, 0, stream>>>(HNF, nfc, AGG, WnuT, bnc, kc0, GN,
                                                    WoN, bnoc, out_nf);
  }
}